// Round 12
// baseline (543.304 us; speedup 1.0000x reference)
//
#include <hip/hip_runtime.h>
#include <hip/hip_bf16.h>

// B=4, S=2048, D=768, H=12, DH=64
// out = [ ctx (B*S*D fp32) | probs (B*H*S*S fp32) ]
#define BB 4
#define SS 2048
#define DD 768
#define HH 12
#define NE 6291456   // BB*SS*DD

typedef unsigned short u16t;
typedef unsigned char  u8t;
typedef unsigned int   u32t;
typedef __attribute__((ext_vector_type(8)))  short bf16x8;
typedef __attribute__((ext_vector_type(4)))  float f32x4;

union FragU { bf16x8 v; ushort4 h[2]; uint4 u; u32t g[4]; };

__device__ __forceinline__ u16t f2bf(float f) {
  union { float fv; u32t u; } x; x.fv = f;
  u32t r = x.u + 0x7FFFu + ((x.u >> 16) & 1u);   // RNE f32 -> bf16
  return (u16t)(r >> 16);
}

__device__ __forceinline__ u32t pkbf2(float a, float b) {  // 2xf32 -> packed bf16x2
  __hip_bfloat162 h2 = __float22bfloat162_rn(make_float2(a, b));
  union { __hip_bfloat162 h; u32t u; } c; c.h = h2;
  return c.u;
}

__device__ __forceinline__ u32t pack4(u32t w) {
  return ((w & 0x01010101u) * 0x01020408u) >> 24;
}
__device__ __forceinline__ u32t pack16b(uint4 v) {
  return pack4(v.x) | (pack4(v.y) << 4) | (pack4(v.z) << 8) | (pack4(v.w) << 12);
}
__device__ __forceinline__ u32t pack_i4(int4 v) {
  return (v.x ? 1u : 0u) | ((v.y ? 1u : 0u) << 1) | ((v.z ? 1u : 0u) << 2) | ((v.w ? 1u : 0u) << 3);
}
__device__ __forceinline__ u32t pack_f4(float4 v) {
  return (v.x != 0.f ? 1u : 0u) | ((v.y != 0.f ? 1u : 0u) << 1) |
         ((v.z != 0.f ? 1u : 0u) << 2) | ((v.w != 0.f ? 1u : 0u) << 3);
}

// ---- mask dtype detector: flag = 0 int32(0/1), 1 bool bytes, 2 float32(0/1) ----
__global__ void detect_kernel(const u32t* __restrict__ mp, int* __restrict__ flag)
{
  __shared__ int s_isb, s_isf;
  if (threadIdx.x == 0) { s_isb = 0; s_isf = 0; }
  __syncthreads();
  int isb = 0, isf = 0;
  for (int i = threadIdx.x; i < 16384; i += 256) {
    u32t v = mp[i];
    if ((v & 0xFF000000u) == 0x3F000000u) isf = 1;
    else if (v & 0xFFFFFF00u) isb = 1;
  }
  if (isb) atomicOr(&s_isb, 1);
  if (isf) atomicOr(&s_isf, 1);
  __syncthreads();
  if (threadIdx.x == 0) *flag = s_isf ? 2 : (s_isb ? 1 : 0);
}

// ---- mask pre-pack: pm[row = b*S+q][c] bit j = mask[b][q][c*32+j]  (2 MB) ----
__global__ __launch_bounds__(256)
void mask_pack_kernel(const void* __restrict__ msk, const int* __restrict__ flagp,
                      u32t* __restrict__ pm)
{
  const int gid = blockIdx.x * 256 + threadIdx.x;   // 0 .. 524287
  const int row = gid >> 6, c = gid & 63;
  const int fmt = *flagp;
  const size_t src = (size_t)(row >> 11) * SS * SS + (size_t)(row & 2047) * SS + c * 32;
  u32t bits;
  if (fmt == 1) {
    const uint4* s = (const uint4*)((const u8t*)msk + src);
    bits = pack16b(s[0]) | (pack16b(s[1]) << 16);
  } else if (fmt == 0) {
    const int4* s = (const int4*)((const int*)msk + src);
    bits = 0;
#pragma unroll
    for (int j = 0; j < 8; ++j) bits |= pack_i4(s[j]) << (j * 4);
  } else {
    const float4* s = (const float4*)((const float*)msk + src);
    bits = 0;
#pragma unroll
    for (int j = 0; j < 8; ++j) bits |= pack_f4(s[j]) << (j * 4);
  }
  pm[(size_t)row * 64 + c] = bits;
}

// ---- X convert: fp32 [8192][768] -> bf16, 3 tensors (grid.y selects) ----
__global__ __launch_bounds__(256)
void cvt_x_kernel(const float* __restrict__ q, const float* __restrict__ k,
                  const float* __restrict__ v, u16t* __restrict__ xb)
{
  const float* src = (blockIdx.y == 0) ? q : (blockIdx.y == 1) ? k : v;
  u16t* dst = xb + (size_t)blockIdx.y * NE;
  const size_t i = ((size_t)blockIdx.x * 256 + threadIdx.x) * 8;
  float4 f0 = *(const float4*)(src + i);
  float4 f1 = *(const float4*)(src + i + 4);
  uint4 o;
  o.x = pkbf2(f0.x, f0.y); o.y = pkbf2(f0.z, f0.w);
  o.z = pkbf2(f1.x, f1.y); o.w = pkbf2(f1.z, f1.w);
  *(uint4*)(dst + i) = o;
}

// ---- W convert+transpose: Wt[n][k] = bf16(W[k][n]); 3 matrices (grid.z) ----
__global__ __launch_bounds__(256)
void cvt_w_kernel(const float* __restrict__ Wq, const float* __restrict__ Wk,
                  const float* __restrict__ Wv, u16t* __restrict__ Wt)
{
  __shared__ u16t T[64 * 72];
  const int t = threadIdx.x;
  const float* W = (blockIdx.z == 0) ? Wq : (blockIdx.z == 1) ? Wk : Wv;
  u16t* wt = Wt + (size_t)blockIdx.z * DD * DD;
  const int n0 = blockIdx.x * 64, k0 = blockIdx.y * 64;
  const int r = t >> 2, cs = (t & 3) * 16;
#pragma unroll
  for (int i = 0; i < 4; ++i) {
    float4 f = *(const float4*)(W + (size_t)(k0 + r) * DD + n0 + cs + i * 4);
    T[(cs + i * 4 + 0) * 72 + r] = f2bf(f.x);
    T[(cs + i * 4 + 1) * 72 + r] = f2bf(f.y);
    T[(cs + i * 4 + 2) * 72 + r] = f2bf(f.z);
    T[(cs + i * 4 + 3) * 72 + r] = f2bf(f.w);
  }
  __syncthreads();
#pragma unroll
  for (int i = 0; i < 2; ++i) {
    uint4 vv = *(const uint4*)&T[r * 72 + cs + i * 8];
    *(uint4*)(wt + (size_t)(n0 + r) * DD + k0 + cs + i * 8) = vv;
  }
}

// ---- proj GEMM core: acc[8] += Xb[m0..+64][:] @ Wt[n0..+128][:]^T ----
__device__ __forceinline__ void proj_core(const u16t* __restrict__ Xrow,
    const u16t* __restrict__ Wrow, u16t* __restrict__ Ab, u16t* __restrict__ Bb,
    int t, f32x4 acc[8])
{
  const int w = t >> 6, l = t & 63;
  const int lq = l & 15, lg = l >> 4;
  const int gr = l >> 3;
  const int gc = ((l & 7) ^ (l >> 3)) * 8;

#define PSTAGE_A(kk_, buf_)                                                       \
  _Pragma("unroll")                                                               \
  for (int j = 0; j < 2; ++j) {                                                   \
    const int rr = (w * 2 + j) * 8 + gr;                                          \
    const u16t* gsrc = Xrow + (size_t)rr * DD + (kk_) + gc;                       \
    __builtin_amdgcn_global_load_lds(                                             \
        (const __attribute__((address_space(1))) void*)gsrc,                      \
        (__attribute__((address_space(3))) void*)(Ab + (buf_) * 4096 + (w * 2 + j) * 512), \
        16, 0, 0);                                                                \
  }
#define PSTAGE_B(kk_, buf_)                                                       \
  _Pragma("unroll")                                                               \
  for (int j = 0; j < 4; ++j) {                                                   \
    const int rr = (w * 4 + j) * 8 + gr;                                          \
    const u16t* gsrc = Wrow + (size_t)rr * DD + (kk_) + gc;                       \
    __builtin_amdgcn_global_load_lds(                                             \
        (const __attribute__((address_space(1))) void*)gsrc,                      \
        (__attribute__((address_space(3))) void*)(Bb + (buf_) * 8192 + (w * 4 + j) * 512), \
        16, 0, 0);                                                                \
  }

  PSTAGE_A(0, 0)
  PSTAGE_B(0, 0)
  __syncthreads();

  const int xa = (lq & 7) * 8;
  for (int kki = 0; kki < 12; ++kki) {
    const int buf = kki & 1;
    if (kki < 11) { PSTAGE_A((kki + 1) * 64, buf ^ 1) PSTAGE_B((kki + 1) * 64, buf ^ 1) }
    const int arow = w * 16 + lq;
    FragU af[2];
#pragma unroll
    for (int ks = 0; ks < 2; ++ks) {
      af[ks].h[0] = *(const ushort4*)&Ab[buf * 4096 + arow * 64 + ((ks * 32 + 4 * lg) ^ xa)];
      af[ks].h[1] = *(const ushort4*)&Ab[buf * 4096 + arow * 64 + ((ks * 32 + 4 * lg + 16) ^ xa)];
    }
#pragma unroll
    for (int nt = 0; nt < 8; ++nt) {
      const int brow = nt * 16 + lq;
#pragma unroll
      for (int ks = 0; ks < 2; ++ks) {
        FragU bf;
        bf.h[0] = *(const ushort4*)&Bb[buf * 8192 + brow * 64 + ((ks * 32 + 4 * lg) ^ xa)];
        bf.h[1] = *(const ushort4*)&Bb[buf * 8192 + brow * 64 + ((ks * 32 + 4 * lg + 16) ^ xa)];
        acc[nt] = __builtin_amdgcn_mfma_f32_16x16x32_bf16(af[ks].v, bf.v, acc[nt], 0, 0, 0);
      }
    }
    __syncthreads();
  }
#undef PSTAGE_A
#undef PSTAGE_B
}

// ---- merged projections: z=0 Q, z=1 K (both [b][h][s][64]); z=2 V ([b][h][dh][s]) ----
__global__ __launch_bounds__(256, 3)
void proj_all_kernel(const u16t* __restrict__ Xb, const u16t* __restrict__ Wt,
                     const float* __restrict__ bq, const float* __restrict__ bk,
                     const float* __restrict__ bv,
                     u16t* __restrict__ Qb, u16t* __restrict__ Kb, u16t* __restrict__ Vb)
{
  __shared__ u16t Ab[2 * 4096];
  __shared__ u16t Bb[2 * 8192];
  const int t = threadIdx.x;
  const int w = t >> 6, l = t & 63;
  const int lq = l & 15, lg = l >> 4;
  const int m0 = blockIdx.x * 64;
  const int n0 = blockIdx.y * 128;
  const int z = blockIdx.z;
  const int b = m0 >> 11;

  const float* bias = (z == 0) ? bq : (z == 1) ? bk : bv;
  u16t* out = (z == 0) ? Qb : (z == 1) ? Kb : Vb;

  f32x4 acc[8];
#pragma unroll
  for (int i = 0; i < 8; ++i)
#pragma unroll
    for (int r = 0; r < 4; ++r) acc[i][r] = 0.f;

  proj_core(Xb + (size_t)z * NE + (size_t)m0 * DD,
            Wt + (size_t)z * DD * DD + (size_t)n0 * DD, Ab, Bb, t, acc);

  if (z < 2) {
#pragma unroll
    for (int nt = 0; nt < 8; ++nt) {
      const int n = n0 + nt * 16 + lq;
      const int h = n >> 6, dh = n & 63;
      const float bb = bias[n];
#pragma unroll
      for (int r = 0; r < 4; ++r) {
        const int s = (m0 & 2047) + w * 16 + 4 * lg + r;
        out[((size_t)(b * HH + h) * SS + s) * 64 + dh] = f2bf(acc[nt][r] + bb);
      }
    }
  } else {
    u16t* Tl = Bb;   // 128 x 72 = 9216 u16, fits in Bb
#pragma unroll
    for (int nt = 0; nt < 8; ++nt) {
      const float bb = bias[n0 + nt * 16 + lq];
#pragma unroll
      for (int r = 0; r < 4; ++r)
        Tl[(nt * 16 + lq) * 72 + w * 16 + 4 * lg + r] = f2bf(acc[nt][r] + bb);
    }
    __syncthreads();
    const int rowl = t >> 1;
    const int half = t & 1;
    const int ncol = n0 + rowl;
    const int h = ncol >> 6, dh = ncol & 63;
    const int s = (m0 & 2047) + half * 32;
    u16t* dst = out + ((size_t)(b * HH + h) * 64 + dh) * SS + s;
#pragma unroll
    for (int i = 0; i < 4; ++i) {
      uint4 vv = *(const uint4*)&Tl[rowl * 72 + half * 32 + i * 8];
      *(uint4*)(dst + i * 8) = vv;
    }
  }
}

// ======== attention, split into two kernels for visibility + RMW isolation ========
// Swapped QK^T (A=K, B=Q): lane(lq,lg) holds S[k=nt*16+4lg+r][q=qbase+lq].

// ---- sweep 1: row exp-sums -> invb[bh*S + q] ----
__global__ __launch_bounds__(256, 4)
void attn_sum_kernel(const u16t* __restrict__ Qh, const u16t* __restrict__ Kh,
                     const u32t* __restrict__ pm, float* __restrict__ invb)
{
  __shared__ u16t KV[3][64 * 64];      // 24 KB ring

  const int t = threadIdx.x;
  const int w = t >> 6, l = t & 63;
  const int lq = l & 15, lg = l >> 4;

  const int bid = (int)blockIdx.x;               // 0..1535
  const int lid = (bid & 7) * 192 + (bid >> 3);  // bijective XCD chunking
  const int bh = lid >> 5;
  const int qt = lid & 31;
  const int b = bh / HH;
  const int qbase = qt * 64 + w * 16;

  const u16t* qh = Qh + (size_t)bh * SS * 64;
  const u16t* kh = Kh + (size_t)bh * SS * 64;

  FragU bq_[2];
  {
    const u16t* qp = qh + (size_t)(qbase + lq) * 64;
#pragma unroll
    for (int ks = 0; ks < 2; ++ks) {
      bq_[ks].h[0] = *(const ushort4*)(qp + ks * 32 + 4 * lg);
      bq_[ks].h[1] = *(const ushort4*)(qp + ks * 32 + 4 * lg + 16);
    }
  }

  const u32t* mrow = pm + ((size_t)b * SS + qbase + lq) * 64;
  const float SC = 0.125f * 1.44269504f;
  const float B4 = 4.0f * 1.44269504f;
  const int gr = l >> 3;
  const int gc = ((l & 7) ^ (l >> 3)) * 8;

#define STAGE_K1(kt_, slot_)                                                      \
  _Pragma("unroll")                                                               \
  for (int j = 0; j < 2; ++j) {                                                   \
    const int rr = (w * 2 + j) * 8 + gr;                                          \
    const u16t* gsrc = kh + (size_t)((kt_) * 64 + rr) * 64 + gc;                  \
    __builtin_amdgcn_global_load_lds(                                             \
        (const __attribute__((address_space(1))) void*)gsrc,                      \
        (__attribute__((address_space(3))) void*)(&KV[slot_][(w * 2 + j) * 512]), \
        16, 0, 0);                                                                \
  }

#define QKT1(nt_, slot_, accv)                                                    \
  {                                                                               \
    const int krow = (nt_) * 16 + lq;                                             \
    const int xr = (lq & 7) * 8;                                                  \
    _Pragma("unroll")                                                             \
    for (int r = 0; r < 4; ++r) (accv)[r] = 0.f;                                  \
    _Pragma("unroll")                                                             \
    for (int ks = 0; ks < 2; ++ks) {                                              \
      FragU ak;                                                                   \
      ak.h[0] = *(const ushort4*)&KV[slot_][krow * 64 + ((ks * 32 + 4 * lg) ^ xr)]; \
      ak.h[1] = *(const ushort4*)&KV[slot_][krow * 64 + ((ks * 32 + 4 * lg + 16) ^ xr)]; \
      (accv) = __builtin_amdgcn_mfma_f32_16x16x32_bf16(ak.v, bq_[ks].v, (accv), 0, 0, 0); \
    }                                                                             \
  }

#define COMPUTE1(slot_, mw_)                                                      \
  {                                                                               \
    _Pragma("unroll")                                                             \
    for (int nt = 0; nt < 4; ++nt) {                                              \
      f32x4 a;                                                                    \
      QKT1(nt, slot_, a)                                                          \
      const u32t word = (nt < 2) ? (mw_).x : (mw_).y;                             \
      const int sh = 16 * (nt & 1) + 4 * lg;                                      \
      _Pragma("unroll")                                                           \
      for (int r = 0; r < 4; ++r) {                                               \
        float s = fmaf(a[r], SC, -B4);                                            \
        if ((word >> (sh + r)) & 1) s = -1.0e9f;                                  \
        ssum += __builtin_exp2f(s);                                               \
      }                                                                           \
    }                                                                             \
  }

  float ssum = 0.f;

  STAGE_K1(0, 0)
  uint2 mA = *(const uint2*)(mrow + 0);
  STAGE_K1(1, 1)
  uint2 mB = *(const uint2*)(mrow + 2);

  for (int kt = 0; kt < 32; kt += 2) {
    if (kt == 0) { asm volatile("s_waitcnt vmcnt(0)" ::: "memory"); }
    else         { asm volatile("s_waitcnt vmcnt(3)" ::: "memory"); }
    __builtin_amdgcn_s_barrier();
    {
      uint2 mw = mA;
      if (kt < 30) { STAGE_K1(kt + 2, (kt + 2) % 3) mA = *(const uint2*)(mrow + (kt + 2) * 2); }
      COMPUTE1(kt % 3, mw)
    }
    if (kt == 0 || kt == 30) { asm volatile("s_waitcnt vmcnt(0)" ::: "memory"); }
    else                     { asm volatile("s_waitcnt vmcnt(3)" ::: "memory"); }
    __builtin_amdgcn_s_barrier();
    {
      uint2 mw = mB;
      if (kt < 30) { STAGE_K1(kt + 3, (kt + 3) % 3) mB = *(const uint2*)(mrow + (kt + 3) * 2); }
      COMPUTE1((kt + 1) % 3, mw)
    }
  }

  ssum += __shfl_xor(ssum, 16);
  ssum += __shfl_xor(ssum, 32);
  if (lg == 0)
    invb[(size_t)bh * SS + qbase + lq] = 1.0f / ssum;
#undef STAGE_K1
#undef QKT1
#undef COMPUTE1
}

// ---- sweep 2: recompute scores -> probs (PLAIN full-bw stores) + PV + ctx ----
__global__ __launch_bounds__(256, 4)
void attn_pv_kernel(const u16t* __restrict__ Qh, const u16t* __restrict__ Kh,
                    const u16t* __restrict__ Vh, const u32t* __restrict__ pm,
                    const float* __restrict__ invb,
                    float* __restrict__ ctx, float* __restrict__ probs)
{
  __shared__ u16t KV[4][64 * 64];      // 32 KB: K dbuf {0,1}, V dbuf {2,3}

  const int t = threadIdx.x;
  const int w = t >> 6, l = t & 63;
  const int lq = l & 15, lg = l >> 4;

  const int bid = (int)blockIdx.x;
  const int lid = (bid & 7) * 192 + (bid >> 3);
  const int bh = lid >> 5;
  const int qt = lid & 31;
  const int b = bh / HH;
  const int qbase = qt * 64 + w * 16;

  const u16t* qh = Qh + (size_t)bh * SS * 64;
  const u16t* kh = Kh + (size_t)bh * SS * 64;
  const u16t* vh = Vh + (size_t)bh * SS * 64;

  FragU bq_[2];
  {
    const u16t* qp = qh + (size_t)(qbase + lq) * 64;
#pragma unroll
    for (int ks = 0; ks < 2; ++ks) {
      bq_[ks].h[0] = *(const ushort4*)(qp + ks * 32 + 4 * lg);
      bq_[ks].h[1] = *(const ushort4*)(qp + ks * 32 + 4 * lg + 16);
    }
  }

  const float inv = invb[(size_t)bh * SS + qbase + lq];

  const u32t* mrow = pm + ((size_t)b * SS + qbase + lq) * 64;
  const float SC = 0.125f * 1.44269504f;
  const float B4 = 4.0f * 1.44269504f;
  const int gr = l >> 3;
  const int gc = ((l & 7) ^ (l >> 3)) * 8;

#define STAGE_K2(kt_, buf_)                                                       \
  _Pragma("unroll")                                                               \
  for (int j = 0; j < 2; ++j) {                                                   \
    const int rr = (w * 2 + j) * 8 + gr;                                          \
    const u16t* gsrc = kh + (size_t)((kt_) * 64 + rr) * 64 + gc;                  \
    __builtin_amdgcn_global_load_lds(                                             \
        (const __attribute__((address_space(1))) void*)gsrc,                      \
        (__attribute__((address_space(3))) void*)(&KV[buf_][(w * 2 + j) * 512]),  \
        16, 0, 0);                                                                \
  }

#define STAGE_V2(kt_, buf_)                                                       \
  _Pragma("unroll")                                                               \
  for (int j = 0; j < 2; ++j) {                                                   \
    const int dv = (w * 2 + j) * 8 + gr;                                          \
    const u16t* gsrc = vh + (size_t)dv * SS + (kt_) * 64 + gc;                    \
    __builtin_amdgcn_global_load_lds(                                             \
        (const __attribute__((address_space(1))) void*)gsrc,                      \
        (__attribute__((address_space(3))) void*)(&KV[2 + (buf_)][(w * 2 + j) * 512]), \
        16, 0, 0);                                                                \
  }

#define QKT2(nt_, buf_, accv)                                                     \
  {                                                                               \
    const int krow = (nt_) * 16 + lq;                                             \
    const int xr = (lq & 7) * 8;                                                  \
    _Pragma("unroll")                                                             \
    for (int r = 0; r < 4; ++r) (accv)[r] = 0.f;                                  \
    _Pragma("unroll")                                                             \
    for (int ks = 0; ks < 2; ++ks) {                                              \
      FragU ak;                                                                   \
      ak.h[0] = *(const ushort4*)&KV[buf_][krow * 64 + ((ks * 32 + 4 * lg) ^ xr)]; \
      ak.h[1] = *(const ushort4*)&KV[buf_][krow * 64 + ((ks * 32 + 4 * lg + 16) ^ xr)]; \
      (accv) = __builtin_amdgcn_mfma_f32_16x16x32_bf16(ak.v, bq_[ks].v, (accv), 0, 0, 0); \
    }                                                                             \
  }

  f32x4 acco[4];
#pragma unroll
  for (int i = 0; i < 4; ++i)
#pragma unroll
    for (int r = 0; r < 4; ++r) acco[i][r] = 0.f;

  const size_t prow = ((size_t)bh * SS + qbase + lq) * SS;

  STAGE_K2(0, 0) STAGE_V2(0, 0)
  uint2 mw2 = *(const uint2*)(mrow + 0);

  for (int kt = 0; kt < 32; ++kt) {
    const int buf = kt & 1;
    if (kt == 0) { asm volatile("s_waitcnt vmcnt(0)" ::: "memory"); }
    else         { asm volatile("s_waitcnt vmcnt(4)" ::: "memory"); }
    __builtin_amdgcn_s_barrier();
    uint2 mw = mw2;
    if (kt < 31) {
      STAGE_K2(kt + 1, buf ^ 1) STAGE_V2(kt + 1, buf ^ 1)
      mw2 = *(const uint2*)(mrow + (kt + 1) * 2);
    }

    // scores -> normalized probs
    f32x4 sc[4];
#pragma unroll
    for (int nt = 0; nt < 4; ++nt) {
      f32x4 a;
      QKT2(nt, buf, a)
      const u32t word = (nt < 2) ? mw.x : mw.y;
      const int sh = 16 * (nt & 1) + 4 * lg;
#pragma unroll
      for (int r = 0; r < 4; ++r) {
        float s = fmaf(a[r], SC, -B4);
        if ((word >> (sh + r)) & 1) s = -1.0e9f;
        sc[nt][r] = __builtin_exp2f(s) * inv;
      }
    }

    // probs: PLAIN stores (no nontemporal) — adjacent nt-pairs complete 128-B
    // lines in L2 before writeback, eliminating partial-line RMW.
#pragma unroll
    for (int nt = 0; nt < 4; ++nt) {
      *(f32x4*)(probs + prow + kt * 64 + nt * 16 + 4 * lg) = sc[nt];
    }

    // pack P for PV A-operand (same k-map as QK^T acc)
    FragU pf[2];
#pragma unroll
    for (int c = 0; c < 2; ++c) {
      pf[c].g[0] = pkbf2(sc[2 * c][0],     sc[2 * c][1]);
      pf[c].g[1] = pkbf2(sc[2 * c][2],     sc[2 * c][3]);
      pf[c].g[2] = pkbf2(sc[2 * c + 1][0], sc[2 * c + 1][1]);
      pf[c].g[3] = pkbf2(sc[2 * c + 1][2], sc[2 * c + 1][3]);
    }

    // PV: O[q][dh] += P(16x64) @ V(64x64); V from KV[2+buf]
    __builtin_amdgcn_s_setprio(1);
#pragma unroll
    for (int c = 0; c < 2; ++c) {
#pragma unroll
      for (int n0 = 0; n0 < 4; ++n0) {
        const int dv = n0 * 16 + lq;
        const int xv = (lq & 7) * 8;
        FragU bvv;
        bvv.h[0] = *(const ushort4*)&KV[2 + buf][dv * 64 + ((c * 32 + 4 * lg) ^ xv)];
        bvv.h[1] = *(const ushort4*)&KV[2 + buf][dv * 64 + ((c * 32 + 4 * lg + 16) ^ xv)];
        acco[n0] = __builtin_amdgcn_mfma_f32_16x16x32_bf16(pf[c].v, bvv.v, acco[n0], 0, 0, 0);
      }
    }
    __builtin_amdgcn_s_setprio(0);
  }

  // ctx epilogue: O[q = qbase+4lg+r][d = h*64 + n0*16 + lq]
  {
    const int h = bh % HH;
    const size_t cbase = (size_t)(b * SS + qbase) * DD + h * 64;
#pragma unroll
    for (int n0 = 0; n0 < 4; ++n0)
#pragma unroll
      for (int r = 0; r < 4; ++r)
        ctx[cbase + (size_t)(4 * lg + r) * DD + n0 * 16 + lq] = acco[n0][r];
  }
#undef STAGE_K2
#undef STAGE_V2
#undef QKT2
}

extern "C" void kernel_launch(void* const* d_in, const int* in_sizes, int n_in,
                              void* d_out, int out_size, void* d_ws, size_t ws_size,
                              hipStream_t stream)
{
  const float* q   = (const float*)d_in[0];
  const float* k   = (const float*)d_in[1];
  const float* v   = (const float*)d_in[2];
  const void*  msk = d_in[3];
  const float* Wq  = (const float*)d_in[4];
  const float* bq  = (const float*)d_in[5];
  const float* Wk  = (const float*)d_in[6];
  const float* bk  = (const float*)d_in[7];
  const float* Wv  = (const float*)d_in[8];
  const float* bv  = (const float*)d_in[9];
  (void)in_sizes; (void)n_in; (void)out_size; (void)ws_size;

  u16t* Qb = (u16t*)d_ws;
  u16t* Kb = Qb + NE;
  u16t* Vb = Kb + NE;
  u32t* pm = (u32t*)(Vb + NE);                      // 2 MB
  float* invb = (float*)(pm + (size_t)BB * SS * 64); // 48*2048 f32 = 393 KB
  int* flag = (int*)(invb + (size_t)BB * HH * SS);

  float* ctx   = (float*)d_out;
  float* probs = ctx + NE;

  // scratch inside probs region (fully overwritten by attn afterwards)
  u16t* Xb = (u16t*)probs;                    // 3 x NE bf16 = 37.7 MB
  u16t* Wt = Xb + (size_t)3 * NE;             // 3 x 768x768 bf16 = 3.5 MB

  detect_kernel<<<1, 256, 0, stream>>>((const u32t*)msk, flag);
  mask_pack_kernel<<<2048, 256, 0, stream>>>(msk, flag, pm);

  cvt_x_kernel<<<dim3(3072, 3), 256, 0, stream>>>(q, k, v, Xb);
  cvt_w_kernel<<<dim3(12, 12, 3), 256, 0, stream>>>(Wq, Wk, Wv, Wt);

  proj_all_kernel<<<dim3(BB * SS / 64, DD / 128, 3), 256, 0, stream>>>(
      Xb, Wt, bq, bk, bv, Qb, Kb, Vb);

  attn_sum_kernel<<<dim3(1536), 256, 0, stream>>>(Qb, Kb, pm, invb);
  attn_pv_kernel <<<dim3(1536), 256, 0, stream>>>(Qb, Kb, Vb, pm, invb, ctx, probs);
}

// Round 13
// 412.567 us; speedup vs baseline: 1.3169x; 1.3169x over previous
//
#include <hip/hip_runtime.h>
#include <hip/hip_bf16.h>

// B=4, S=2048, D=768, H=12, DH=64
// out = [ ctx (B*S*D fp32) | probs (B*H*S*S fp32) ]
#define BB 4
#define SS 2048
#define DD 768
#define HH 12
#define NE 6291456   // BB*SS*DD

typedef unsigned short u16t;
typedef unsigned char  u8t;
typedef unsigned int   u32t;
typedef __attribute__((ext_vector_type(8)))  short bf16x8;
typedef __attribute__((ext_vector_type(4)))  float f32x4;

union FragU { bf16x8 v; ushort4 h[2]; uint4 u; u32t g[4]; };

__device__ __forceinline__ u16t f2bf(float f) {
  union { float fv; u32t u; } x; x.fv = f;
  u32t r = x.u + 0x7FFFu + ((x.u >> 16) & 1u);   // RNE f32 -> bf16
  return (u16t)(r >> 16);
}

__device__ __forceinline__ u32t pkbf2(float a, float b) {  // 2xf32 -> packed bf16x2
  __hip_bfloat162 h2 = __float22bfloat162_rn(make_float2(a, b));
  union { __hip_bfloat162 h; u32t u; } c; c.h = h2;
  return c.u;
}

__device__ __forceinline__ u32t pack4(u32t w) {
  return ((w & 0x01010101u) * 0x01020408u) >> 24;
}
__device__ __forceinline__ u32t pack16b(uint4 v) {
  return pack4(v.x) | (pack4(v.y) << 4) | (pack4(v.z) << 8) | (pack4(v.w) << 12);
}
__device__ __forceinline__ u32t pack_i4(int4 v) {
  return (v.x ? 1u : 0u) | ((v.y ? 1u : 0u) << 1) | ((v.z ? 1u : 0u) << 2) | ((v.w ? 1u : 0u) << 3);
}
__device__ __forceinline__ u32t pack_f4(float4 v) {
  return (v.x != 0.f ? 1u : 0u) | ((v.y != 0.f ? 1u : 0u) << 1) |
         ((v.z != 0.f ? 1u : 0u) << 2) | ((v.w != 0.f ? 1u : 0u) << 3);
}

// ---- mask dtype detector: flag = 0 int32(0/1), 1 bool bytes, 2 float32(0/1) ----
__global__ void detect_kernel(const u32t* __restrict__ mp, int* __restrict__ flag)
{
  __shared__ int s_isb, s_isf;
  if (threadIdx.x == 0) { s_isb = 0; s_isf = 0; }
  __syncthreads();
  int isb = 0, isf = 0;
  for (int i = threadIdx.x; i < 16384; i += 256) {
    u32t v = mp[i];
    if ((v & 0xFF000000u) == 0x3F000000u) isf = 1;
    else if (v & 0xFFFFFF00u) isb = 1;
  }
  if (isb) atomicOr(&s_isb, 1);
  if (isf) atomicOr(&s_isf, 1);
  __syncthreads();
  if (threadIdx.x == 0) *flag = s_isf ? 2 : (s_isb ? 1 : 0);
}

// ---- mask pre-pack: pm[row = b*S+q][c] bit j = mask[b][q][c*32+j]  (2 MB) ----
__global__ __launch_bounds__(256)
void mask_pack_kernel(const void* __restrict__ msk, const int* __restrict__ flagp,
                      u32t* __restrict__ pm)
{
  const int gid = blockIdx.x * 256 + threadIdx.x;   // 0 .. 524287
  const int row = gid >> 6, c = gid & 63;
  const int fmt = *flagp;
  const size_t src = (size_t)(row >> 11) * SS * SS + (size_t)(row & 2047) * SS + c * 32;
  u32t bits;
  if (fmt == 1) {
    const uint4* s = (const uint4*)((const u8t*)msk + src);
    bits = pack16b(s[0]) | (pack16b(s[1]) << 16);
  } else if (fmt == 0) {
    const int4* s = (const int4*)((const int*)msk + src);
    bits = 0;
#pragma unroll
    for (int j = 0; j < 8; ++j) bits |= pack_i4(s[j]) << (j * 4);
  } else {
    const float4* s = (const float4*)((const float*)msk + src);
    bits = 0;
#pragma unroll
    for (int j = 0; j < 8; ++j) bits |= pack_f4(s[j]) << (j * 4);
  }
  pm[(size_t)row * 64 + c] = bits;
}

// ---- X convert: fp32 [8192][768] -> bf16, 3 tensors (grid.y selects) ----
__global__ __launch_bounds__(256)
void cvt_x_kernel(const float* __restrict__ q, const float* __restrict__ k,
                  const float* __restrict__ v, u16t* __restrict__ xb)
{
  const float* src = (blockIdx.y == 0) ? q : (blockIdx.y == 1) ? k : v;
  u16t* dst = xb + (size_t)blockIdx.y * NE;
  const size_t i = ((size_t)blockIdx.x * 256 + threadIdx.x) * 8;
  float4 f0 = *(const float4*)(src + i);
  float4 f1 = *(const float4*)(src + i + 4);
  uint4 o;
  o.x = pkbf2(f0.x, f0.y); o.y = pkbf2(f0.z, f0.w);
  o.z = pkbf2(f1.x, f1.y); o.w = pkbf2(f1.z, f1.w);
  *(uint4*)(dst + i) = o;
}

// ---- W convert+transpose: Wt[n][k] = bf16(W[k][n]); 3 matrices (grid.z) ----
__global__ __launch_bounds__(256)
void cvt_w_kernel(const float* __restrict__ Wq, const float* __restrict__ Wk,
                  const float* __restrict__ Wv, u16t* __restrict__ Wt)
{
  __shared__ u16t T[64 * 72];
  const int t = threadIdx.x;
  const float* W = (blockIdx.z == 0) ? Wq : (blockIdx.z == 1) ? Wk : Wv;
  u16t* wt = Wt + (size_t)blockIdx.z * DD * DD;
  const int n0 = blockIdx.x * 64, k0 = blockIdx.y * 64;
  const int r = t >> 2, cs = (t & 3) * 16;
#pragma unroll
  for (int i = 0; i < 4; ++i) {
    float4 f = *(const float4*)(W + (size_t)(k0 + r) * DD + n0 + cs + i * 4);
    T[(cs + i * 4 + 0) * 72 + r] = f2bf(f.x);
    T[(cs + i * 4 + 1) * 72 + r] = f2bf(f.y);
    T[(cs + i * 4 + 2) * 72 + r] = f2bf(f.z);
    T[(cs + i * 4 + 3) * 72 + r] = f2bf(f.w);
  }
  __syncthreads();
#pragma unroll
  for (int i = 0; i < 2; ++i) {
    uint4 vv = *(const uint4*)&T[r * 72 + cs + i * 8];
    *(uint4*)(wt + (size_t)(n0 + r) * DD + k0 + cs + i * 8) = vv;
  }
}

// ---- proj GEMM core: acc[8] += Xb[m0..+64][:] @ Wt[n0..+128][:]^T ----
__device__ __forceinline__ void proj_core(const u16t* __restrict__ Xrow,
    const u16t* __restrict__ Wrow, u16t* __restrict__ Ab, u16t* __restrict__ Bb,
    int t, f32x4 acc[8])
{
  const int w = t >> 6, l = t & 63;
  const int lq = l & 15, lg = l >> 4;
  const int gr = l >> 3;
  const int gc = ((l & 7) ^ (l >> 3)) * 8;

#define PSTAGE_A(kk_, buf_)                                                       \
  _Pragma("unroll")                                                               \
  for (int j = 0; j < 2; ++j) {                                                   \
    const int rr = (w * 2 + j) * 8 + gr;                                          \
    const u16t* gsrc = Xrow + (size_t)rr * DD + (kk_) + gc;                       \
    __builtin_amdgcn_global_load_lds(                                             \
        (const __attribute__((address_space(1))) void*)gsrc,                      \
        (__attribute__((address_space(3))) void*)(Ab + (buf_) * 4096 + (w * 2 + j) * 512), \
        16, 0, 0);                                                                \
  }
#define PSTAGE_B(kk_, buf_)                                                       \
  _Pragma("unroll")                                                               \
  for (int j = 0; j < 4; ++j) {                                                   \
    const int rr = (w * 4 + j) * 8 + gr;                                          \
    const u16t* gsrc = Wrow + (size_t)rr * DD + (kk_) + gc;                       \
    __builtin_amdgcn_global_load_lds(                                             \
        (const __attribute__((address_space(1))) void*)gsrc,                      \
        (__attribute__((address_space(3))) void*)(Bb + (buf_) * 8192 + (w * 4 + j) * 512), \
        16, 0, 0);                                                                \
  }

  PSTAGE_A(0, 0)
  PSTAGE_B(0, 0)
  __syncthreads();

  const int xa = (lq & 7) * 8;
  for (int kki = 0; kki < 12; ++kki) {
    const int buf = kki & 1;
    if (kki < 11) { PSTAGE_A((kki + 1) * 64, buf ^ 1) PSTAGE_B((kki + 1) * 64, buf ^ 1) }
    const int arow = w * 16 + lq;
    FragU af[2];
#pragma unroll
    for (int ks = 0; ks < 2; ++ks) {
      af[ks].h[0] = *(const ushort4*)&Ab[buf * 4096 + arow * 64 + ((ks * 32 + 4 * lg) ^ xa)];
      af[ks].h[1] = *(const ushort4*)&Ab[buf * 4096 + arow * 64 + ((ks * 32 + 4 * lg + 16) ^ xa)];
    }
#pragma unroll
    for (int nt = 0; nt < 8; ++nt) {
      const int brow = nt * 16 + lq;
#pragma unroll
      for (int ks = 0; ks < 2; ++ks) {
        FragU bf;
        bf.h[0] = *(const ushort4*)&Bb[buf * 8192 + brow * 64 + ((ks * 32 + 4 * lg) ^ xa)];
        bf.h[1] = *(const ushort4*)&Bb[buf * 8192 + brow * 64 + ((ks * 32 + 4 * lg + 16) ^ xa)];
        acc[nt] = __builtin_amdgcn_mfma_f32_16x16x32_bf16(af[ks].v, bf.v, acc[nt], 0, 0, 0);
      }
    }
    __syncthreads();
  }
#undef PSTAGE_A
#undef PSTAGE_B
}

// ---- merged projections: z=0 Q, z=1 K (both [b][h][s][64]); z=2 V ([b][h][dh][s]) ----
__global__ __launch_bounds__(256, 3)
void proj_all_kernel(const u16t* __restrict__ Xb, const u16t* __restrict__ Wt,
                     const float* __restrict__ bq, const float* __restrict__ bk,
                     const float* __restrict__ bv,
                     u16t* __restrict__ Qb, u16t* __restrict__ Kb, u16t* __restrict__ Vb)
{
  __shared__ u16t Ab[2 * 4096];
  __shared__ u16t Bb[2 * 8192];
  const int t = threadIdx.x;
  const int w = t >> 6, l = t & 63;
  const int lq = l & 15, lg = l >> 4;
  const int m0 = blockIdx.x * 64;
  const int n0 = blockIdx.y * 128;
  const int z = blockIdx.z;
  const int b = m0 >> 11;

  const float* bias = (z == 0) ? bq : (z == 1) ? bk : bv;
  u16t* out = (z == 0) ? Qb : (z == 1) ? Kb : Vb;

  f32x4 acc[8];
#pragma unroll
  for (int i = 0; i < 8; ++i)
#pragma unroll
    for (int r = 0; r < 4; ++r) acc[i][r] = 0.f;

  proj_core(Xb + (size_t)z * NE + (size_t)m0 * DD,
            Wt + (size_t)z * DD * DD + (size_t)n0 * DD, Ab, Bb, t, acc);

  if (z < 2) {
#pragma unroll
    for (int nt = 0; nt < 8; ++nt) {
      const int n = n0 + nt * 16 + lq;
      const int h = n >> 6, dh = n & 63;
      const float bb = bias[n];
#pragma unroll
      for (int r = 0; r < 4; ++r) {
        const int s = (m0 & 2047) + w * 16 + 4 * lg + r;
        out[((size_t)(b * HH + h) * SS + s) * 64 + dh] = f2bf(acc[nt][r] + bb);
      }
    }
  } else {
    u16t* Tl = Bb;   // 128 x 72 = 9216 u16, fits in Bb
#pragma unroll
    for (int nt = 0; nt < 8; ++nt) {
      const float bb = bias[n0 + nt * 16 + lq];
#pragma unroll
      for (int r = 0; r < 4; ++r)
        Tl[(nt * 16 + lq) * 72 + w * 16 + 4 * lg + r] = f2bf(acc[nt][r] + bb);
    }
    __syncthreads();
    const int rowl = t >> 1;
    const int half = t & 1;
    const int ncol = n0 + rowl;
    const int h = ncol >> 6, dh = ncol & 63;
    const int s = (m0 & 2047) + half * 32;
    u16t* dst = out + ((size_t)(b * HH + h) * 64 + dh) * SS + s;
#pragma unroll
    for (int i = 0; i < 4; ++i) {
      uint4 vv = *(const uint4*)&Tl[rowl * 72 + half * 32 + i * 8];
      *(uint4*)(dst + i * 8) = vv;
    }
  }
}

// ---- fused attention: r8/r11 structure + 128-row q-blocks (2 groups/wave) ----
// Swapped QK^T (A=K, B=Q): lane(lq,lg) holds S[k=nt*16+4lg+r][q=qgbase(g)+lq].
// NT stores (proven essential, r12). Counted vmcnt; stores never drained in-loop.
// KV slots: sweep1 K-ring = {0,1,2}; sweep2 K dbuf {0,1}, V dbuf {2,3}.
__global__ __launch_bounds__(256, 3)
void attn_kernel(const u16t* __restrict__ Qh, const u16t* __restrict__ Kh,
                 const u16t* __restrict__ Vh, const u32t* __restrict__ pm,
                 float* __restrict__ ctx, float* __restrict__ probs)
{
  __shared__ u16t KV[4][64 * 64];      // 32 KB total

  const int t = threadIdx.x;
  const int w = t >> 6, l = t & 63;
  const int lq = l & 15, lg = l >> 4;

  const int bid = (int)blockIdx.x;               // 0..767
  const int lid = (bid & 7) * 96 + (bid >> 3);   // bijective XCD chunking (768 = 8*96)
  const int bh = lid >> 4;                       // 0..47
  const int qt = lid & 15;                       // 0..15
  const int b = bh / HH;
  const int qbase = qt * 128 + w * 32;           // wave owns 32 q-rows (2 groups of 16)

  const u16t* qh = Qh + (size_t)bh * SS * 64;
  const u16t* kh = Kh + (size_t)bh * SS * 64;
  const u16t* vh = Vh + (size_t)bh * SS * 64;

  // Q fragments, 2 groups: bq_[g][ks] = Q[qbase + g*16 + lq][ks*32 + ...]
  FragU bq_[2][2];
#pragma unroll
  for (int g = 0; g < 2; ++g) {
    const u16t* qp = qh + (size_t)(qbase + g * 16 + lq) * 64;
#pragma unroll
    for (int ks = 0; ks < 2; ++ks) {
      bq_[g][ks].h[0] = *(const ushort4*)(qp + ks * 32 + 4 * lg);
      bq_[g][ks].h[1] = *(const ushort4*)(qp + ks * 32 + 4 * lg + 16);
    }
  }

  const u32t* mrow0 = pm + ((size_t)b * SS + qbase + lq) * 64;
  const u32t* mrow1 = mrow0 + 16 * 64;

  const float SC = 0.125f * 1.44269504f;
  const float B4 = 4.0f * 1.44269504f;

  const int gr = l >> 3;
  const int gc = ((l & 7) ^ (l >> 3)) * 8;

#define STAGE_K(kt_, slot_)                                                       \
  _Pragma("unroll")                                                               \
  for (int j = 0; j < 2; ++j) {                                                   \
    const int rr = (w * 2 + j) * 8 + gr;                                          \
    const u16t* gsrc = kh + (size_t)((kt_) * 64 + rr) * 64 + gc;                  \
    __builtin_amdgcn_global_load_lds(                                             \
        (const __attribute__((address_space(1))) void*)gsrc,                      \
        (__attribute__((address_space(3))) void*)(&KV[slot_][(w * 2 + j) * 512]), \
        16, 0, 0);                                                                \
  }

#define STAGE_V(kt_, vbuf_)                                                       \
  _Pragma("unroll")                                                               \
  for (int j = 0; j < 2; ++j) {                                                   \
    const int dv = (w * 2 + j) * 8 + gr;                                          \
    const u16t* gsrc = vh + (size_t)dv * SS + (kt_) * 64 + gc;                    \
    __builtin_amdgcn_global_load_lds(                                             \
        (const __attribute__((address_space(1))) void*)gsrc,                      \
        (__attribute__((address_space(3))) void*)(&KV[2 + (vbuf_)][(w * 2 + j) * 512]), \
        16, 0, 0);                                                                \
  }

#define QKT_CHUNK(nt_, slot_, g_, accv)                                           \
  {                                                                               \
    const int krow = (nt_) * 16 + lq;                                             \
    const int xr = (lq & 7) * 8;                                                  \
    _Pragma("unroll")                                                             \
    for (int r = 0; r < 4; ++r) (accv)[r] = 0.f;                                  \
    _Pragma("unroll")                                                             \
    for (int ks = 0; ks < 2; ++ks) {                                              \
      FragU ak;                                                                   \
      ak.h[0] = *(const ushort4*)&KV[slot_][krow * 64 + ((ks * 32 + 4 * lg) ^ xr)]; \
      ak.h[1] = *(const ushort4*)&KV[slot_][krow * 64 + ((ks * 32 + 4 * lg + 16) ^ xr)]; \
      (accv) = __builtin_amdgcn_mfma_f32_16x16x32_bf16(ak.v, bq_[g_][ks].v, (accv), 0, 0, 0); \
    }                                                                             \
  }

  // sweep-1 per-tile compute, both groups
#define COMPUTE1(slot_, m0_, m1_)                                                 \
  {                                                                               \
    _Pragma("unroll")                                                             \
    for (int nt = 0; nt < 4; ++nt) {                                              \
      f32x4 a;                                                                    \
      QKT_CHUNK(nt, slot_, 0, a)                                                  \
      const u32t word = (nt < 2) ? (m0_).x : (m0_).y;                             \
      const int sh = 16 * (nt & 1) + 4 * lg;                                      \
      _Pragma("unroll")                                                           \
      for (int r = 0; r < 4; ++r) {                                               \
        float s = fmaf(a[r], SC, -B4);                                            \
        if ((word >> (sh + r)) & 1) s = -1.0e9f;                                  \
        ssum0 += __builtin_exp2f(s);                                              \
      }                                                                           \
    }                                                                             \
    _Pragma("unroll")                                                             \
    for (int nt = 0; nt < 4; ++nt) {                                              \
      f32x4 a;                                                                    \
      QKT_CHUNK(nt, slot_, 1, a)                                                  \
      const u32t word = (nt < 2) ? (m1_).x : (m1_).y;                             \
      const int sh = 16 * (nt & 1) + 4 * lg;                                      \
      _Pragma("unroll")                                                           \
      for (int r = 0; r < 4; ++r) {                                               \
        float s = fmaf(a[r], SC, -B4);                                            \
        if ((word >> (sh + r)) & 1) s = -1.0e9f;                                  \
        ssum1 += __builtin_exp2f(s);                                              \
      }                                                                           \
    }                                                                             \
  }

  float ssum0 = 0.f, ssum1 = 0.f;

  // ---------------- sweep 1: K-only, 3-ring slots 0..2, depth-2 ----------------
  STAGE_K(0, 0)
  uint2 mA0 = *(const uint2*)(mrow0 + 0);
  uint2 mA1 = *(const uint2*)(mrow1 + 0);
  STAGE_K(1, 1)
  uint2 mB0 = *(const uint2*)(mrow0 + 2);
  uint2 mB1 = *(const uint2*)(mrow1 + 2);

  for (int kt = 0; kt < 32; kt += 2) {
    asm volatile("s_waitcnt vmcnt(4)" ::: "memory");
    __builtin_amdgcn_s_barrier();
    {
      uint2 m0 = mA0, m1 = mA1;
      if (kt < 30) {
        STAGE_K(kt + 2, (kt + 2) % 3)
        mA0 = *(const uint2*)(mrow0 + (kt + 2) * 2);
        mA1 = *(const uint2*)(mrow1 + (kt + 2) * 2);
      }
      COMPUTE1(kt % 3, m0, m1)
    }
    if (kt == 30) { asm volatile("s_waitcnt vmcnt(0)" ::: "memory"); }
    else          { asm volatile("s_waitcnt vmcnt(4)" ::: "memory"); }
    __builtin_amdgcn_s_barrier();
    {
      uint2 m0 = mB0, m1 = mB1;
      if (kt < 30) {
        STAGE_K(kt + 3, (kt + 3) % 3)
        mB0 = *(const uint2*)(mrow0 + (kt + 3) * 2);
        mB1 = *(const uint2*)(mrow1 + (kt + 3) * 2);
      }
      COMPUTE1((kt + 1) % 3, m0, m1)
    }
  }

  ssum0 += __shfl_xor(ssum0, 16);
  ssum0 += __shfl_xor(ssum0, 32);
  ssum1 += __shfl_xor(ssum1, 16);
  ssum1 += __shfl_xor(ssum1, 32);
  const float inv0 = 1.0f / ssum0;
  const float inv1 = 1.0f / ssum1;

  f32x4 acco[2][4];
#pragma unroll
  for (int g = 0; g < 2; ++g)
#pragma unroll
    for (int i = 0; i < 4; ++i)
#pragma unroll
      for (int r = 0; r < 4; ++r) acco[g][i][r] = 0.f;

  const size_t prow0 = ((size_t)bh * SS + qbase + lq) * SS;
  const size_t prow1 = prow0 + (size_t)16 * SS;

  // ---------------- sweep 2: K dbuf {0,1} + V dbuf {2,3}, depth-1, vmcnt(8) ----------------
  __builtin_amdgcn_s_barrier();          // all waves done reading sweep-1 ring
  STAGE_K(0, 0) STAGE_V(0, 0)
  uint2 mw20 = *(const uint2*)(mrow0 + 0);
  uint2 mw21 = *(const uint2*)(mrow1 + 0);

  for (int kt = 0; kt < 32; ++kt) {
    const int buf = kt & 1;
    if (kt == 0) { asm volatile("s_waitcnt vmcnt(0)" ::: "memory"); }
    else         { asm volatile("s_waitcnt vmcnt(8)" ::: "memory"); }
    __builtin_amdgcn_s_barrier();
    uint2 m0 = mw20, m1 = mw21;
    if (kt < 31) {
      STAGE_K(kt + 1, buf ^ 1) STAGE_V(kt + 1, buf ^ 1)
      mw20 = *(const uint2*)(mrow0 + (kt + 1) * 2);
      mw21 = *(const uint2*)(mrow1 + (kt + 1) * 2);
    }

    // ---- group 0 ----
    {
      f32x4 sc[4];
#pragma unroll
      for (int nt = 0; nt < 4; ++nt) {
        f32x4 a;
        QKT_CHUNK(nt, buf, 0, a)
        const u32t word = (nt < 2) ? m0.x : m0.y;
        const int sh = 16 * (nt & 1) + 4 * lg;
#pragma unroll
        for (int r = 0; r < 4; ++r) {
          float s = fmaf(a[r], SC, -B4);
          if ((word >> (sh + r)) & 1) s = -1.0e9f;
          sc[nt][r] = __builtin_exp2f(s) * inv0;
        }
      }
#pragma unroll
      for (int nt = 0; nt < 4; ++nt)
        __builtin_nontemporal_store(sc[nt], (f32x4*)(probs + prow0 + kt * 64 + nt * 16 + 4 * lg));
      FragU pf[2];
#pragma unroll
      for (int c = 0; c < 2; ++c) {
        pf[c].g[0] = pkbf2(sc[2 * c][0],     sc[2 * c][1]);
        pf[c].g[1] = pkbf2(sc[2 * c][2],     sc[2 * c][3]);
        pf[c].g[2] = pkbf2(sc[2 * c + 1][0], sc[2 * c + 1][1]);
        pf[c].g[3] = pkbf2(sc[2 * c + 1][2], sc[2 * c + 1][3]);
      }
      __builtin_amdgcn_s_setprio(1);
#pragma unroll
      for (int c = 0; c < 2; ++c) {
#pragma unroll
        for (int n0 = 0; n0 < 4; ++n0) {
          const int dv = n0 * 16 + lq;
          const int xv = (lq & 7) * 8;
          FragU bvv;
          bvv.h[0] = *(const ushort4*)&KV[2 + buf][dv * 64 + ((c * 32 + 4 * lg) ^ xv)];
          bvv.h[1] = *(const ushort4*)&KV[2 + buf][dv * 64 + ((c * 32 + 4 * lg + 16) ^ xv)];
          acco[0][n0] = __builtin_amdgcn_mfma_f32_16x16x32_bf16(pf[c].v, bvv.v, acco[0][n0], 0, 0, 0);
        }
      }
      __builtin_amdgcn_s_setprio(0);
    }
    // ---- group 1 ----
    {
      f32x4 sc[4];
#pragma unroll
      for (int nt = 0; nt < 4; ++nt) {
        f32x4 a;
        QKT_CHUNK(nt, buf, 1, a)
        const u32t word = (nt < 2) ? m1.x : m1.y;
        const int sh = 16 * (nt & 1) + 4 * lg;
#pragma unroll
        for (int r = 0; r < 4; ++r) {
          float s = fmaf(a[r], SC, -B4);
          if ((word >> (sh + r)) & 1) s = -1.0e9f;
          sc[nt][r] = __builtin_exp2f(s) * inv1;
        }
      }
#pragma unroll
      for (int nt = 0; nt < 4; ++nt)
        __builtin_nontemporal_store(sc[nt], (f32x4*)(probs + prow1 + kt * 64 + nt * 16 + 4 * lg));
      FragU pf[2];
#pragma unroll
      for (int c = 0; c < 2; ++c) {
        pf[c].g[0] = pkbf2(sc[2 * c][0],     sc[2 * c][1]);
        pf[c].g[1] = pkbf2(sc[2 * c][2],     sc[2 * c][3]);
        pf[c].g[2] = pkbf2(sc[2 * c + 1][0], sc[2 * c + 1][1]);
        pf[c].g[3] = pkbf2(sc[2 * c + 1][2], sc[2 * c + 1][3]);
      }
      __builtin_amdgcn_s_setprio(1);
#pragma unroll
      for (int c = 0; c < 2; ++c) {
#pragma unroll
        for (int n0 = 0; n0 < 4; ++n0) {
          const int dv = n0 * 16 + lq;
          const int xv = (lq & 7) * 8;
          FragU bvv;
          bvv.h[0] = *(const ushort4*)&KV[2 + buf][dv * 64 + ((c * 32 + 4 * lg) ^ xv)];
          bvv.h[1] = *(const ushort4*)&KV[2 + buf][dv * 64 + ((c * 32 + 4 * lg + 16) ^ xv)];
          acco[1][n0] = __builtin_amdgcn_mfma_f32_16x16x32_bf16(pf[c].v, bvv.v, acco[1][n0], 0, 0, 0);
        }
      }
      __builtin_amdgcn_s_setprio(0);
    }
  }

  // ctx epilogue: O[q = qbase + g*16 + 4lg + r][d = h*64 + n0*16 + lq]
  {
    const int h = bh % HH;
#pragma unroll
    for (int g = 0; g < 2; ++g) {
      const size_t cbase = (size_t)(b * SS + qbase + g * 16) * DD + h * 64;
#pragma unroll
      for (int n0 = 0; n0 < 4; ++n0)
#pragma unroll
        for (int r = 0; r < 4; ++r)
          ctx[cbase + (size_t)(4 * lg + r) * DD + n0 * 16 + lq] = acco[g][n0][r];
    }
  }
#undef STAGE_K
#undef STAGE_V
#undef QKT_CHUNK
#undef COMPUTE1
}

extern "C" void kernel_launch(void* const* d_in, const int* in_sizes, int n_in,
                              void* d_out, int out_size, void* d_ws, size_t ws_size,
                              hipStream_t stream)
{
  const float* q   = (const float*)d_in[0];
  const float* k   = (const float*)d_in[1];
  const float* v   = (const float*)d_in[2];
  const void*  msk = d_in[3];
  const float* Wq  = (const float*)d_in[4];
  const float* bq  = (const float*)d_in[5];
  const float* Wk  = (const float*)d_in[6];
  const float* bk  = (const float*)d_in[7];
  const float* Wv  = (const float*)d_in[8];
  const float* bv  = (const float*)d_in[9];
  (void)in_sizes; (void)n_in; (void)out_size; (void)ws_size;

  u16t* Qb = (u16t*)d_ws;
  u16t* Kb = Qb + NE;
  u16t* Vb = Kb + NE;
  u32t* pm = (u32t*)(Vb + NE);                // 2 MB
  int* flag = (int*)(pm + (size_t)BB * SS * 64);

  float* ctx   = (float*)d_out;
  float* probs = ctx + NE;

  // scratch inside probs region (fully overwritten by attn afterwards)
  u16t* Xb = (u16t*)probs;                    // 3 x NE bf16 = 37.7 MB
  u16t* Wt = Xb + (size_t)3 * NE;             // 3 x 768x768 bf16 = 3.5 MB

  detect_kernel<<<1, 256, 0, stream>>>((const u32t*)msk, flag);
  mask_pack_kernel<<<2048, 256, 0, stream>>>(msk, flag, pm);

  cvt_x_kernel<<<dim3(3072, 3), 256, 0, stream>>>(q, k, v, Xb);
  cvt_w_kernel<<<dim3(12, 12, 3), 256, 0, stream>>>(Wq, Wk, Wv, Wt);

  proj_all_kernel<<<dim3(BB * SS / 64, DD / 128, 3), 256, 0, stream>>>(
      Xb, Wt, bq, bk, bv, Qb, Kb, Vb);

  attn_kernel<<<dim3(768), 256, 0, stream>>>(Qb, Kb, Vb, pm, ctx, probs);
}

// Round 14
// 376.158 us; speedup vs baseline: 1.4444x; 1.0968x over previous
//
#include <hip/hip_runtime.h>
#include <hip/hip_bf16.h>

// B=4, S=2048, D=768, H=12, DH=64
// out = [ ctx (B*S*D fp32) | probs (B*H*S*S fp32) ]
#define BB 4
#define SS 2048
#define DD 768
#define HH 12
#define NE 6291456   // BB*SS*DD

typedef unsigned short u16t;
typedef unsigned char  u8t;
typedef unsigned int   u32t;
typedef __attribute__((ext_vector_type(8)))  short bf16x8;
typedef __attribute__((ext_vector_type(4)))  float f32x4;

union FragU { bf16x8 v; ushort4 h[2]; uint4 u; u32t g[4]; };

__device__ __forceinline__ u16t f2bf(float f) {
  union { float fv; u32t u; } x; x.fv = f;
  u32t r = x.u + 0x7FFFu + ((x.u >> 16) & 1u);   // RNE f32 -> bf16
  return (u16t)(r >> 16);
}

__device__ __forceinline__ u32t pkbf2(float a, float b) {  // 2xf32 -> packed bf16x2
  __hip_bfloat162 h2 = __float22bfloat162_rn(make_float2(a, b));
  union { __hip_bfloat162 h; u32t u; } c; c.h = h2;
  return c.u;
}

__device__ __forceinline__ u32t pack4(u32t w) {
  return ((w & 0x01010101u) * 0x01020408u) >> 24;
}
__device__ __forceinline__ u32t pack16b(uint4 v) {
  return pack4(v.x) | (pack4(v.y) << 4) | (pack4(v.z) << 8) | (pack4(v.w) << 12);
}
__device__ __forceinline__ u32t pack_i4(int4 v) {
  return (v.x ? 1u : 0u) | ((v.y ? 1u : 0u) << 1) | ((v.z ? 1u : 0u) << 2) | ((v.w ? 1u : 0u) << 3);
}
__device__ __forceinline__ u32t pack_f4(float4 v) {
  return (v.x != 0.f ? 1u : 0u) | ((v.y != 0.f ? 1u : 0u) << 1) |
         ((v.z != 0.f ? 1u : 0u) << 2) | ((v.w != 0.f ? 1u : 0u) << 3);
}

// ---- merged prep: cvt_x (blocks 0..9215) + cvt_w (9216..9647) + detect (9648) ----
__global__ __launch_bounds__(256)
void prep_kernel(const float* __restrict__ q, const float* __restrict__ k,
                 const float* __restrict__ v,
                 const float* __restrict__ Wq, const float* __restrict__ Wk,
                 const float* __restrict__ Wv,
                 const u32t* __restrict__ mp,
                 u16t* __restrict__ xb, u16t* __restrict__ Wt, int* __restrict__ flag)
{
  __shared__ u16t T[64 * 72];
  const int bid = (int)blockIdx.x;
  const int t = threadIdx.x;

  if (bid < 9216) {            // cvt_x: fp32 [8192][768] -> bf16, 3 tensors
    const int y = bid / 3072, x = bid % 3072;
    const float* src = (y == 0) ? q : (y == 1) ? k : v;
    u16t* dst = xb + (size_t)y * NE;
    const size_t i = ((size_t)x * 256 + t) * 8;
    float4 f0 = *(const float4*)(src + i);
    float4 f1 = *(const float4*)(src + i + 4);
    uint4 o;
    o.x = pkbf2(f0.x, f0.y); o.y = pkbf2(f0.z, f0.w);
    o.z = pkbf2(f1.x, f1.y); o.w = pkbf2(f1.z, f1.w);
    *(uint4*)(dst + i) = o;
  } else if (bid < 9648) {     // cvt_w: Wt[n][k] = bf16(W[k][n])
    const int r0 = bid - 9216;
    const int z = r0 / 144, rem = r0 % 144;
    const int n0 = (rem % 12) * 64, k0 = (rem / 12) * 64;
    const float* W = (z == 0) ? Wq : (z == 1) ? Wk : Wv;
    u16t* wt = Wt + (size_t)z * DD * DD;
    const int r = t >> 2, cs = (t & 3) * 16;
#pragma unroll
    for (int i = 0; i < 4; ++i) {
      float4 f = *(const float4*)(W + (size_t)(k0 + r) * DD + n0 + cs + i * 4);
      T[(cs + i * 4 + 0) * 72 + r] = f2bf(f.x);
      T[(cs + i * 4 + 1) * 72 + r] = f2bf(f.y);
      T[(cs + i * 4 + 2) * 72 + r] = f2bf(f.z);
      T[(cs + i * 4 + 3) * 72 + r] = f2bf(f.w);
    }
    __syncthreads();
#pragma unroll
    for (int i = 0; i < 2; ++i) {
      uint4 vv = *(const uint4*)&T[r * 72 + cs + i * 8];
      *(uint4*)(wt + (size_t)(n0 + r) * DD + k0 + cs + i * 8) = vv;
    }
  } else {                     // detect: flag = 0 int32, 1 bool bytes, 2 float32
    __shared__ int s_isb, s_isf;
    if (t == 0) { s_isb = 0; s_isf = 0; }
    __syncthreads();
    int isb = 0, isf = 0;
    for (int i = t; i < 16384; i += 256) {
      u32t vv = mp[i];
      if ((vv & 0xFF000000u) == 0x3F000000u) isf = 1;
      else if (vv & 0xFFFFFF00u) isb = 1;
    }
    if (isb) atomicOr(&s_isb, 1);
    if (isf) atomicOr(&s_isf, 1);
    __syncthreads();
    if (t == 0) *flag = s_isf ? 2 : (s_isb ? 1 : 0);
  }
}

// ---- proj GEMM core: acc[8] += Xb[m0..+64][:] @ Wt[n0..+128][:]^T ----
__device__ __forceinline__ void proj_core(const u16t* __restrict__ Xrow,
    const u16t* __restrict__ Wrow, u16t* __restrict__ Ab, u16t* __restrict__ Bb,
    int t, f32x4 acc[8])
{
  const int w = t >> 6, l = t & 63;
  const int lq = l & 15, lg = l >> 4;
  const int gr = l >> 3;
  const int gc = ((l & 7) ^ (l >> 3)) * 8;

#define PSTAGE_A(kk_, buf_)                                                       \
  _Pragma("unroll")                                                               \
  for (int j = 0; j < 2; ++j) {                                                   \
    const int rr = (w * 2 + j) * 8 + gr;                                          \
    const u16t* gsrc = Xrow + (size_t)rr * DD + (kk_) + gc;                       \
    __builtin_amdgcn_global_load_lds(                                             \
        (const __attribute__((address_space(1))) void*)gsrc,                      \
        (__attribute__((address_space(3))) void*)(Ab + (buf_) * 4096 + (w * 2 + j) * 512), \
        16, 0, 0);                                                                \
  }
#define PSTAGE_B(kk_, buf_)                                                       \
  _Pragma("unroll")                                                               \
  for (int j = 0; j < 4; ++j) {                                                   \
    const int rr = (w * 4 + j) * 8 + gr;                                          \
    const u16t* gsrc = Wrow + (size_t)rr * DD + (kk_) + gc;                       \
    __builtin_amdgcn_global_load_lds(                                             \
        (const __attribute__((address_space(1))) void*)gsrc,                      \
        (__attribute__((address_space(3))) void*)(Bb + (buf_) * 8192 + (w * 4 + j) * 512), \
        16, 0, 0);                                                                \
  }

  PSTAGE_A(0, 0)
  PSTAGE_B(0, 0)
  __syncthreads();

  const int xa = (lq & 7) * 8;
  for (int kki = 0; kki < 12; ++kki) {
    const int buf = kki & 1;
    if (kki < 11) { PSTAGE_A((kki + 1) * 64, buf ^ 1) PSTAGE_B((kki + 1) * 64, buf ^ 1) }
    const int arow = w * 16 + lq;
    FragU af[2];
#pragma unroll
    for (int ks = 0; ks < 2; ++ks) {
      af[ks].h[0] = *(const ushort4*)&Ab[buf * 4096 + arow * 64 + ((ks * 32 + 4 * lg) ^ xa)];
      af[ks].h[1] = *(const ushort4*)&Ab[buf * 4096 + arow * 64 + ((ks * 32 + 4 * lg + 16) ^ xa)];
    }
#pragma unroll
    for (int nt = 0; nt < 8; ++nt) {
      const int brow = nt * 16 + lq;
#pragma unroll
      for (int ks = 0; ks < 2; ++ks) {
        FragU bf;
        bf.h[0] = *(const ushort4*)&Bb[buf * 8192 + brow * 64 + ((ks * 32 + 4 * lg) ^ xa)];
        bf.h[1] = *(const ushort4*)&Bb[buf * 8192 + brow * 64 + ((ks * 32 + 4 * lg + 16) ^ xa)];
        acc[nt] = __builtin_amdgcn_mfma_f32_16x16x32_bf16(af[ks].v, bf.v, acc[nt], 0, 0, 0);
      }
    }
    __syncthreads();
  }
#undef PSTAGE_A
#undef PSTAGE_B
}

// ---- merged projections + mask_pack ----
// blocks 0..2303: proj (z = bid/768: 0 Q, 1 K, 2 V-transposed); 2304..4351: mask_pack
__global__ __launch_bounds__(256, 3)
void proj_mask_kernel(const u16t* __restrict__ Xb, const u16t* __restrict__ Wt,
                      const float* __restrict__ bq, const float* __restrict__ bk,
                      const float* __restrict__ bv,
                      u16t* __restrict__ Qb, u16t* __restrict__ Kb, u16t* __restrict__ Vb,
                      const void* __restrict__ msk, const int* __restrict__ flagp,
                      u32t* __restrict__ pm)
{
  __shared__ u16t Ab[2 * 4096];
  __shared__ u16t Bb[2 * 8192];
  const int bid = (int)blockIdx.x;
  const int t = threadIdx.x;

  if (bid >= 2304) {   // ---- mask_pack ----
    const int gid = (bid - 2304) * 256 + t;   // 0 .. 524287
    const int row = gid >> 6, c = gid & 63;
    const int fmt = *flagp;
    const size_t src = (size_t)(row >> 11) * SS * SS + (size_t)(row & 2047) * SS + c * 32;
    u32t bits;
    if (fmt == 1) {
      const uint4* s = (const uint4*)((const u8t*)msk + src);
      bits = pack16b(s[0]) | (pack16b(s[1]) << 16);
    } else if (fmt == 0) {
      const int4* s = (const int4*)((const int*)msk + src);
      bits = 0;
#pragma unroll
      for (int j = 0; j < 8; ++j) bits |= pack_i4(s[j]) << (j * 4);
    } else {
      const float4* s = (const float4*)((const float*)msk + src);
      bits = 0;
#pragma unroll
      for (int j = 0; j < 8; ++j) bits |= pack_f4(s[j]) << (j * 4);
    }
    pm[(size_t)row * 64 + c] = bits;
    return;
  }

  // ---- proj ----
  const int z = bid / 768;
  const int rem = bid % 768;
  const int m0 = (rem % 128) * 64;
  const int n0 = (rem / 128) * 128;
  const int w = t >> 6, l = t & 63;
  const int lq = l & 15, lg = l >> 4;
  const int b = m0 >> 11;

  const float* bias = (z == 0) ? bq : (z == 1) ? bk : bv;
  u16t* out = (z == 0) ? Qb : (z == 1) ? Kb : Vb;

  f32x4 acc[8];
#pragma unroll
  for (int i = 0; i < 8; ++i)
#pragma unroll
    for (int r = 0; r < 4; ++r) acc[i][r] = 0.f;

  proj_core(Xb + (size_t)z * NE + (size_t)m0 * DD,
            Wt + (size_t)z * DD * DD + (size_t)n0 * DD, Ab, Bb, t, acc);

  if (z < 2) {
#pragma unroll
    for (int nt = 0; nt < 8; ++nt) {
      const int n = n0 + nt * 16 + lq;
      const int h = n >> 6, dh = n & 63;
      const float bb = bias[n];
#pragma unroll
      for (int r = 0; r < 4; ++r) {
        const int s = (m0 & 2047) + w * 16 + 4 * lg + r;
        out[((size_t)(b * HH + h) * SS + s) * 64 + dh] = f2bf(acc[nt][r] + bb);
      }
    }
  } else {
    u16t* Tl = Bb;
#pragma unroll
    for (int nt = 0; nt < 8; ++nt) {
      const float bb = bias[n0 + nt * 16 + lq];
#pragma unroll
      for (int r = 0; r < 4; ++r)
        Tl[(nt * 16 + lq) * 72 + w * 16 + 4 * lg + r] = f2bf(acc[nt][r] + bb);
    }
    __syncthreads();
    const int rowl = t >> 1;
    const int half = t & 1;
    const int ncol = n0 + rowl;
    const int h = ncol >> 6, dh = ncol & 63;
    const int s = (m0 & 2047) + half * 32;
    u16t* dst = out + ((size_t)(b * HH + h) * 64 + dh) * SS + s;
#pragma unroll
    for (int i = 0; i < 4; ++i) {
      uint4 vv = *(const uint4*)&Tl[rowl * 72 + half * 32 + i * 8];
      *(uint4*)(dst + i * 8) = vv;
    }
  }
}

// ---- fused attention: r7-champion structure (3-buf K+V, depth-2, NT stores),
//      sweep-2 gates re-derived to NEVER retire in-flight stores:
//      confirm stage(t)+mask(t) needs only vmcnt(ops-issued-after) = 21 steady.
__global__ __launch_bounds__(256, 3)
void attn_kernel(const u16t* __restrict__ Qh, const u16t* __restrict__ Kh,
                 const u16t* __restrict__ Vh, const u32t* __restrict__ pm,
                 float* __restrict__ ctx, float* __restrict__ probs)
{
  __shared__ u16t Kb3[3][64 * 64];   // 24 KB
  __shared__ u16t Vb3[3][64 * 64];   // 24 KB

  const int t = threadIdx.x;
  const int w = t >> 6, l = t & 63;
  const int lq = l & 15, lg = l >> 4;

  const int bid = (int)blockIdx.x;               // 0..1535
  const int lid = (bid & 7) * 192 + (bid >> 3);  // bijective XCD chunking
  const int bh = lid >> 5;                       // 0..47
  const int qt = lid & 31;                       // 0..31
  const int b = bh / HH;
  const int qbase = qt * 64 + w * 16;

  const u16t* qh = Qh + (size_t)bh * SS * 64;
  const u16t* kh = Kh + (size_t)bh * SS * 64;
  const u16t* vh = Vh + (size_t)bh * SS * 64;

  FragU bq_[2];
  {
    const u16t* qp = qh + (size_t)(qbase + lq) * 64;
#pragma unroll
    for (int ks = 0; ks < 2; ++ks) {
      bq_[ks].h[0] = *(const ushort4*)(qp + ks * 32 + 4 * lg);
      bq_[ks].h[1] = *(const ushort4*)(qp + ks * 32 + 4 * lg + 16);
    }
  }

  const u32t* mrow = pm + ((size_t)b * SS + qbase + lq) * 64;

  const float SC = 0.125f * 1.44269504f;
  const float B4 = 4.0f * 1.44269504f;

  const int gr = l >> 3;
  const int gc = ((l & 7) ^ (l >> 3)) * 8;

#define STAGE_K(kt_, buf_)                                                        \
  _Pragma("unroll")                                                               \
  for (int j = 0; j < 2; ++j) {                                                   \
    const int rr = (w * 2 + j) * 8 + gr;                                          \
    const u16t* gsrc = kh + (size_t)((kt_) * 64 + rr) * 64 + gc;                  \
    __builtin_amdgcn_global_load_lds(                                             \
        (const __attribute__((address_space(1))) void*)gsrc,                      \
        (__attribute__((address_space(3))) void*)(&Kb3[buf_][(w * 2 + j) * 512]), \
        16, 0, 0);                                                                \
  }

#define STAGE_V(kt_, buf_)                                                        \
  _Pragma("unroll")                                                               \
  for (int j = 0; j < 2; ++j) {                                                   \
    const int dv = (w * 2 + j) * 8 + gr;                                          \
    const u16t* gsrc = vh + (size_t)dv * SS + (kt_) * 64 + gc;                    \
    __builtin_amdgcn_global_load_lds(                                             \
        (const __attribute__((address_space(1))) void*)gsrc,                      \
        (__attribute__((address_space(3))) void*)(&Vb3[buf_][(w * 2 + j) * 512]), \
        16, 0, 0);                                                                \
  }

#define QKT_CHUNK(nt_, buf_, accv)                                                \
  {                                                                               \
    const int krow = (nt_) * 16 + lq;                                             \
    const int xr = (lq & 7) * 8;                                                  \
    _Pragma("unroll")                                                             \
    for (int r = 0; r < 4; ++r) (accv)[r] = 0.f;                                  \
    _Pragma("unroll")                                                             \
    for (int ks = 0; ks < 2; ++ks) {                                              \
      FragU ak;                                                                   \
      ak.h[0] = *(const ushort4*)&Kb3[buf_][krow * 64 + ((ks * 32 + 4 * lg) ^ xr)]; \
      ak.h[1] = *(const ushort4*)&Kb3[buf_][krow * 64 + ((ks * 32 + 4 * lg + 16) ^ xr)]; \
      (accv) = __builtin_amdgcn_mfma_f32_16x16x32_bf16(ak.v, bq_[ks].v, (accv), 0, 0, 0); \
    }                                                                             \
  }

#define COMPUTE1(buf_, mw_)                                                       \
  {                                                                               \
    _Pragma("unroll")                                                             \
    for (int nt = 0; nt < 4; ++nt) {                                              \
      f32x4 a;                                                                    \
      QKT_CHUNK(nt, buf_, a)                                                      \
      const u32t word = (nt < 2) ? (mw_).x : (mw_).y;                             \
      const int sh = 16 * (nt & 1) + 4 * lg;                                      \
      _Pragma("unroll")                                                           \
      for (int r = 0; r < 4; ++r) {                                               \
        float s = fmaf(a[r], SC, -B4);                                            \
        if ((word >> (sh + r)) & 1) s = -1.0e9f;                                  \
        ssum += __builtin_exp2f(s);                                               \
      }                                                                           \
    }                                                                             \
  }

#define COMPUTE2(kt_, buf_, mw_)                                                  \
  {                                                                               \
    f32x4 sc[4];                                                                  \
    _Pragma("unroll")                                                             \
    for (int nt = 0; nt < 4; ++nt) {                                              \
      f32x4 a;                                                                    \
      QKT_CHUNK(nt, buf_, a)                                                      \
      const u32t word = (nt < 2) ? (mw_).x : (mw_).y;                             \
      const int sh = 16 * (nt & 1) + 4 * lg;                                      \
      _Pragma("unroll")                                                           \
      for (int r = 0; r < 4; ++r) {                                               \
        float s = fmaf(a[r], SC, -B4);                                            \
        if ((word >> (sh + r)) & 1) s = -1.0e9f;                                  \
        sc[nt][r] = __builtin_exp2f(s) * inv;                                     \
      }                                                                           \
    }                                                                             \
    _Pragma("unroll")                                                             \
    for (int nt = 0; nt < 4; ++nt) {                                              \
      __builtin_nontemporal_store(sc[nt],                                         \
          (f32x4*)(probs + prow + (kt_) * 64 + nt * 16 + 4 * lg));                \
    }                                                                             \
    FragU pf[2];                                                                  \
    _Pragma("unroll")                                                             \
    for (int c = 0; c < 2; ++c) {                                                 \
      pf[c].g[0] = pkbf2(sc[2 * c][0],     sc[2 * c][1]);                         \
      pf[c].g[1] = pkbf2(sc[2 * c][2],     sc[2 * c][3]);                         \
      pf[c].g[2] = pkbf2(sc[2 * c + 1][0], sc[2 * c + 1][1]);                     \
      pf[c].g[3] = pkbf2(sc[2 * c + 1][2], sc[2 * c + 1][3]);                     \
    }                                                                             \
    __builtin_amdgcn_s_setprio(1);                                                \
    _Pragma("unroll")                                                             \
    for (int c = 0; c < 2; ++c) {                                                 \
      _Pragma("unroll")                                                           \
      for (int n0 = 0; n0 < 4; ++n0) {                                            \
        const int dv = n0 * 16 + lq;                                              \
        const int xv = (lq & 7) * 8;                                              \
        FragU bvv;                                                                \
        bvv.h[0] = *(const ushort4*)&Vb3[buf_][dv * 64 + ((c * 32 + 4 * lg) ^ xv)]; \
        bvv.h[1] = *(const ushort4*)&Vb3[buf_][dv * 64 + ((c * 32 + 4 * lg + 16) ^ xv)]; \
        acco[n0] = __builtin_amdgcn_mfma_f32_16x16x32_bf16(pf[c].v, bvv.v, acco[n0], 0, 0, 0); \
      }                                                                           \
    }                                                                             \
    __builtin_amdgcn_s_setprio(0);                                                \
  }

  float ssum = 0.f;

  // ---------------- sweep 1: K-only, 3-buf, depth-2, masks reg-prefetched ----------------
  STAGE_K(0, 0)
  uint2 mA = *(const uint2*)(mrow + 0);
  STAGE_K(1, 1)
  uint2 mB = *(const uint2*)(mrow + 2);

  for (int kt = 0; kt < 32; kt += 2) {
    if (kt == 0) { asm volatile("s_waitcnt vmcnt(3)" ::: "memory"); }
    else         { asm volatile("s_waitcnt vmcnt(3)" ::: "memory"); }
    __builtin_amdgcn_s_barrier();
    {
      uint2 mw = mA;
      if (kt < 30) { STAGE_K(kt + 2, (kt + 2) % 3) mA = *(const uint2*)(mrow + (kt + 2) * 2); }
      COMPUTE1(kt % 3, mw)
    }
    if (kt == 30) { asm volatile("s_waitcnt vmcnt(0)" ::: "memory"); }
    else          { asm volatile("s_waitcnt vmcnt(3)" ::: "memory"); }
    __builtin_amdgcn_s_barrier();
    {
      uint2 mw = mB;
      if (kt < 30) { STAGE_K(kt + 3, (kt + 3) % 3) mB = *(const uint2*)(mrow + (kt + 3) * 2); }
      COMPUTE1((kt + 1) % 3, mw)
    }
  }

  ssum += __shfl_xor(ssum, 16);
  ssum += __shfl_xor(ssum, 32);
  const float inv = 1.0f / ssum;

  f32x4 acco[4];
#pragma unroll
  for (int i = 0; i < 4; ++i)
#pragma unroll
    for (int r = 0; r < 4; ++r) acco[i][r] = 0.f;

  const size_t prow = ((size_t)bh * SS + qbase + lq) * SS;

  // ---------------- sweep 2: K+V 3-buf depth-2; minimal gates (stores never retired) ----------------
  __builtin_amdgcn_s_barrier();          // all waves done reading sweep-1 bufs
  STAGE_K(0, 0) STAGE_V(0, 0)
  uint2 mA2 = *(const uint2*)(mrow + 0);
  STAGE_K(1, 1) STAGE_V(1, 1)
  uint2 mB2 = *(const uint2*)(mrow + 2);

  // Per-iter VMEM ops: stage K(2)+V(2) + mask(1) + stores(8).
  // Gate = #ops issued after [stage(t), mask(t)]:
  //   t=0: stage(1)(4)+mask(1) = 5; t=1: stage(2)(4)+mask(1)+stores(0)(8) = 13;
  //   steady: stores(t-2)(8)+stage(t+1)(4)+mask(1)+stores(t-1)(8) = 21;
  //   t=30: 21; t=31: stores(29)(8)+stores(30)(8) = 16.
  for (int kt = 0; kt < 32; kt += 2) {
    if (kt == 0)  { asm volatile("s_waitcnt vmcnt(5)"  ::: "memory"); }
    else          { asm volatile("s_waitcnt vmcnt(21)" ::: "memory"); }
    __builtin_amdgcn_s_barrier();
    {
      uint2 mw = mA2;
      if (kt < 30) {
        STAGE_K(kt + 2, (kt + 2) % 3) STAGE_V(kt + 2, (kt + 2) % 3)
        mA2 = *(const uint2*)(mrow + (kt + 2) * 2);
      }
      COMPUTE2(kt, kt % 3, mw)
    }
    if (kt == 0)       { asm volatile("s_waitcnt vmcnt(13)" ::: "memory"); }
    else if (kt == 30) { asm volatile("s_waitcnt vmcnt(16)" ::: "memory"); }
    else               { asm volatile("s_waitcnt vmcnt(21)" ::: "memory"); }
    __builtin_amdgcn_s_barrier();
    {
      uint2 mw = mB2;
      if (kt < 30) {
        STAGE_K(kt + 3, (kt + 3) % 3) STAGE_V(kt + 3, (kt + 3) % 3)
        mB2 = *(const uint2*)(mrow + (kt + 3) * 2);
      }
      COMPUTE2(kt + 1, (kt + 1) % 3, mw)
    }
  }

  // ctx epilogue: O[q = qbase+4lg+r][d = h*64 + n0*16 + lq]
  {
    const int h = bh % HH;
    const size_t cbase = (size_t)(b * SS + qbase) * DD + h * 64;
#pragma unroll
    for (int n0 = 0; n0 < 4; ++n0)
#pragma unroll
      for (int r = 0; r < 4; ++r)
        ctx[cbase + (size_t)(4 * lg + r) * DD + n0 * 16 + lq] = acco[n0][r];
  }
#undef STAGE_K
#undef STAGE_V
#undef QKT_CHUNK
#undef COMPUTE1
#undef COMPUTE2
}

extern "C" void kernel_launch(void* const* d_in, const int* in_sizes, int n_in,
                              void* d_out, int out_size, void* d_ws, size_t ws_size,
                              hipStream_t stream)
{
  const float* q   = (const float*)d_in[0];
  const float* k   = (const float*)d_in[1];
  const float* v   = (const float*)d_in[2];
  const void*  msk = d_in[3];
  const float* Wq  = (const float*)d_in[4];
  const float* bq  = (const float*)d_in[5];
  const float* Wk  = (const float*)d_in[6];
  const float* bk  = (const float*)d_in[7];
  const float* Wv  = (const float*)d_in[8];
  const float* bv  = (const float*)d_in[9];
  (void)in_sizes; (void)n_in; (void)out_size; (void)ws_size;

  u16t* Qb = (u16t*)d_ws;
  u16t* Kb = Qb + NE;
  u16t* Vb = Kb + NE;
  u32t* pm = (u32t*)(Vb + NE);                // 2 MB
  int* flag = (int*)(pm + (size_t)BB * SS * 64);

  float* ctx   = (float*)d_out;
  float* probs = ctx + NE;

  // scratch inside probs region (fully overwritten by attn afterwards)
  u16t* Xb = (u16t*)probs;                    // 3 x NE bf16 = 37.7 MB
  u16t* Wt = Xb + (size_t)3 * NE;             // 3 x 768x768 bf16 = 3.5 MB

  prep_kernel<<<dim3(9649), 256, 0, stream>>>(q, k, v, Wq, Wk, Wv,
                                              (const u32t*)msk, Xb, Wt, flag);

  proj_mask_kernel<<<dim3(4352), 256, 0, stream>>>(Xb, Wt, bq, bk, bv,
                                                   Qb, Kb, Vb, msk, flag, pm);

  attn_kernel<<<dim3(1536), 256, 0, stream>>>(Qb, Kb, Vb, pm, ctx, probs);
}